// Round 9
// baseline (213.648 us; speedup 1.0000x reference)
//
#include <hip/hip_runtime.h>
#include <hip/hip_cooperative_groups.h>

namespace cg = cooperative_groups;

#define NUM_LAYERS 1000
#define DIM 10
#define STRIDE 112           // floats per affine slot (10x11 = 110, padded to 112)
#define LPB 16               // layers per chunk
#define NBLK 63              // ceil(1000/16)
#define WQ4 320              // float4 per wave in apply (64 lanes * 5)
#define TILE_Q4 1280         // float4 per block (4 waves)

// Affine stored col-major in a slot: slot[j*10 + r] = M[r][j] for j<10,
// slot[100 + r] = c[r]. Compose dst = g(f(.)): col_j(dst) = M_g * col_j(f)
// (+ c_g when j==10). Lane j (0..10) owns column j.
__device__ inline void compose_one(const float* __restrict__ src,
                                   float* __restrict__ dst,
                                   int c, int lane) {
    const float* F = src + (size_t)(2 * c) * STRIDE;
    const float* G = src + (size_t)(2 * c + 1) * STRIDE;
    float colf[DIM], o[DIM];
    #pragma unroll
    for (int r = 0; r < DIM; ++r) colf[r] = F[lane * DIM + r];
    #pragma unroll
    for (int r = 0; r < DIM; ++r) {
        float acc = (lane == DIM) ? G[100 + r] : 0.f;
        #pragma unroll
        for (int k = 0; k < DIM; ++k)
            acc += G[k * DIM + r] * colf[k];
        o[r] = acc;
    }
    float* D = dst + (size_t)c * STRIDE;
    #pragma unroll
    for (int r = 0; r < DIM; ++r) D[lane * DIM + r] = o[r];
}

// LDS union: phase 1 and phase 2 never overlap (separated by grid.sync).
union CSmem {
    struct { float a[LPB * STRIDE]; float b[(LPB / 2) * STRIDE]; } p1;  // 10.8 KB
    struct { float a[64 * STRIDE];  float b[32 * STRIDE];       } p2;  // 43.0 KB
};

// ---------------------------------------------------------------------------
// Cooperative compose: 63 blocks each fold 16 layers (proven 4-wave tree,
// verified in round 7's fused kernel), grid.sync(), then block 0 folds the
// 63 chunk affines (proven tree64 structure, 4-wave variant). Cross-XCD
// handoff: plain stores + __threadfence (release) before grid.sync; agent-
// scope relaxed atomic loads after (round-1/7-verified pattern). Writes the
// final affine ROW-major: aff[r*10+k] = M[r][k], aff[100+r] = c[r].
// ---------------------------------------------------------------------------
__global__ __launch_bounds__(256) void compose_coop(const float* __restrict__ Ws,
                                                    const float* __restrict__ bs,
                                                    float* __restrict__ ws_chunks,
                                                    float* __restrict__ aff) {
    __shared__ CSmem u;
    const int tid = threadIdx.x;
    const int w = tid >> 6, lane = tid & 63;
    const int bid = blockIdx.x;

    // ---- phase 1: this block's 16 layers -> one chunk affine ----
    for (int e = tid; e < LPB * 100; e += 256) {
        int ll = e / 100, rem = e % 100;      // rem = r*10 + k
        int r = rem / 10, k = rem % 10;
        int l = bid * LPB + ll;
        float v = (l < NUM_LAYERS) ? Ws[(size_t)l * 100 + rem]
                                   : (r == k ? 1.f : 0.f);
        u.p1.a[ll * STRIDE + k * DIM + r] = v;
    }
    for (int e = tid; e < LPB * DIM; e += 256) {
        int ll = e / DIM, r = e % DIM;
        int l = bid * LPB + ll;
        float v = (l < NUM_LAYERS) ? bs[(size_t)l * DIM + r] : 0.f;
        u.p1.a[ll * STRIDE + 100 + r] = v;
    }

    {   // 4-level tree: 16 -> 8 -> 4 -> 2 -> 1 (4 waves, c += 4)
        const float* src = u.p1.a;
        float* dst = u.p1.b;
        for (int n = LPB / 2; n >= 1; n >>= 1) {
            __syncthreads();
            if (lane <= DIM)
                for (int c = w; c < n; c += 4) compose_one(src, dst, c, lane);
            const float* t = dst; dst = (float*)src; src = t;
        }
        __syncthreads();               // 4 levels (even) -> result in u.p1.a == src
        if (tid < 110) ws_chunks[(size_t)bid * STRIDE + tid] = src[tid];
    }

    __threadfence();                   // release chunk stores to agent scope
    cg::this_grid().sync();

    if (bid != 0) return;

    // ---- phase 2 (block 0): fold 63 chunks (padded to 64 with identity) ----
    for (int e = tid; e < 64 * STRIDE; e += 256) {
        int chunk = e / STRIDE, pos = e % STRIDE;
        float v;
        if (pos >= 110)        v = 0.f;
        else if (chunk < NBLK) v = __hip_atomic_load(&ws_chunks[e], __ATOMIC_RELAXED,
                                                     __HIP_MEMORY_SCOPE_AGENT);
        else v = (pos < 100 && (pos / 10 == pos % 10)) ? 1.f : 0.f;  // identity
        u.p2.a[e] = v;
    }

    const float* src = u.p2.a;
    float* dst = u.p2.b;
    for (int n = 32; n >= 1; n >>= 1) {        // 6 levels: 32,16,8,4,2,1
        __syncthreads();
        if (lane <= DIM)
            for (int c = w; c < n; c += 4) compose_one(src, dst, c, lane);
        const float* t = dst; dst = (float*)src; src = t;
    }
    __syncthreads();                   // even #levels -> result in u.p2.a == src
    if (tid < 110) {
        if (tid < 100) {
            int j = tid / DIM, r = tid % DIM;  // src[j*10+r] = M[r][j]
            aff[r * DIM + j] = src[tid];
        } else {
            aff[tid] = src[tid];               // bias
        }
    }
}

// ---------------------------------------------------------------------------
// K3 (FROZEN round-5 kernel, 47.8 us, 0 bank conflicts): out = M x + c.
// Barrier-free: each wave owns a private 5 KB LDS region, redistributes
// coalesced<->row-contiguous intra-wave, ordered by lgkmcnt(0) +
// sched_barrier(0) (rule #18). No __syncthreads. All global traffic is
// lane-contiguous float4. LDS read stride 80 B = conflict-free.
// ---------------------------------------------------------------------------
__global__ __launch_bounds__(256) void apply_affine(const float* __restrict__ x,
                                                    const float* __restrict__ aff,
                                                    float* __restrict__ out,
                                                    int nq4) {
    __shared__ float4 lds4[4][WQ4];
    __shared__ float4 s4[28];                  // 112 floats (110 used)
    const int tid  = threadIdx.x;
    const int w    = tid >> 6, lane = tid & 63;
    const float* __restrict__ s = (const float*)s4;

    if (lane < 28) s4[lane] = ((const float4*)aff)[lane];

    const int q0 = blockIdx.x * TILE_Q4 + w * WQ4;   // this wave's float4 base
    const float4* __restrict__ xin = (const float4*)x + q0;
    float4* __restrict__ op = (float4*)out + q0;
    const int rem = nq4 - q0;                  // float4s this wave still owns

    float4 r0, r1, r2, r3, r4;
    if (0 * 64 + lane < rem) r0 = xin[0 * 64 + lane];
    if (1 * 64 + lane < rem) r1 = xin[1 * 64 + lane];
    if (2 * 64 + lane < rem) r2 = xin[2 * 64 + lane];
    if (3 * 64 + lane < rem) r3 = xin[3 * 64 + lane];
    if (4 * 64 + lane < rem) r4 = xin[4 * 64 + lane];

    lds4[w][0 * 64 + lane] = r0;
    lds4[w][1 * 64 + lane] = r1;
    lds4[w][2 * 64 + lane] = r2;
    lds4[w][3 * 64 + lane] = r3;
    lds4[w][4 * 64 + lane] = r4;

    asm volatile("s_waitcnt lgkmcnt(0)" ::: "memory");
    __builtin_amdgcn_sched_barrier(0);

    float xv[20];
    #pragma unroll
    for (int i = 0; i < 5; ++i) {
        float4 v = lds4[w][5 * lane + i];
        xv[4*i+0] = v.x; xv[4*i+1] = v.y; xv[4*i+2] = v.z; xv[4*i+3] = v.w;
    }

    float o[20];
    #pragma unroll
    for (int rr = 0; rr < 2; ++rr)
        #pragma unroll
        for (int j = 0; j < DIM; ++j) {
            float acc = s[100 + j];
            #pragma unroll
            for (int k = 0; k < DIM; ++k)
                acc += s[j * DIM + k] * xv[rr * DIM + k];
            o[rr * DIM + j] = acc;
        }

    #pragma unroll
    for (int i = 0; i < 5; ++i)
        lds4[w][5 * lane + i] = make_float4(o[4*i+0], o[4*i+1], o[4*i+2], o[4*i+3]);

    asm volatile("s_waitcnt lgkmcnt(0)" ::: "memory");
    __builtin_amdgcn_sched_barrier(0);

    {
        float4 t0 = lds4[w][0 * 64 + lane];
        float4 t1 = lds4[w][1 * 64 + lane];
        float4 t2 = lds4[w][2 * 64 + lane];
        float4 t3 = lds4[w][3 * 64 + lane];
        float4 t4 = lds4[w][4 * 64 + lane];
        if (0 * 64 + lane < rem) op[0 * 64 + lane] = t0;
        if (1 * 64 + lane < rem) op[1 * 64 + lane] = t1;
        if (2 * 64 + lane < rem) op[2 * 64 + lane] = t2;
        if (3 * 64 + lane < rem) op[3 * 64 + lane] = t3;
        if (4 * 64 + lane < rem) op[4 * 64 + lane] = t4;
    }
}

extern "C" void kernel_launch(void* const* d_in, const int* in_sizes, int n_in,
                              void* d_out, int out_size, void* d_ws, size_t ws_size,
                              hipStream_t stream) {
    const float* x  = (const float*)d_in[0];   // [BATCH, 10]
    const float* Ws = (const float*)d_in[1];   // [1000, 10, 10]
    const float* bs = (const float*)d_in[2];   // [1000, 10]
    float* out = (float*)d_out;

    float* ws_chunks = (float*)d_ws;                      // NBLK * STRIDE floats
    float* ws_aff    = ws_chunks + NBLK * STRIDE;         // 112 floats (16B aligned)

    {   // one cooperative dispatch replaces compose16 + compose_tree64
        void* args[] = {(void*)&Ws, (void*)&bs, (void*)&ws_chunks, (void*)&ws_aff};
        hipLaunchCooperativeKernel((void*)compose_coop, dim3(NBLK), dim3(256),
                                   args, 0, stream);
    }

    const int nq4 = in_sizes[0] / 4;                      // in_sizes is in floats
    const int blocks = (nq4 + TILE_Q4 - 1) / TILE_Q4;
    apply_affine<<<blocks, 256, 0, stream>>>(x, ws_aff, out, nq4);
}

// Round 10
// 165.084 us; speedup vs baseline: 1.2942x; 1.2942x over previous
//
#include <hip/hip_runtime.h>

#define NUM_LAYERS 1000
#define DIM 10
#define STRIDE 112           // floats per affine slot (10x11 = 110, padded to 112)
#define LPB 16               // layers per block in K1
#define NBLK 63              // ceil(1000/16)
#define WQ4 320              // float4 per wave in apply (64 lanes * 5)
#define TILE_Q4 1280         // float4 per block (4 waves)

// Direct global->LDS DMA, 16 B per lane. LDS dest is wave-uniform base +
// lane*16 (m104/m108); global src is per-lane. Counter: vmcnt.
__device__ inline void gload_lds16(const void* g, void* l) {
    __builtin_amdgcn_global_load_lds(
        (const __attribute__((address_space(1))) void*)g,
        (__attribute__((address_space(3))) void*)l, 16, 0, 0);
}

// Affine stored col-major in a slot: slot[j*10 + r] = M[r][j] for j<10,
// slot[100 + r] = c[r]. Compose dst = g(f(.)): col_j(dst) = M_g * col_j(f)
// (+ c_g when j==10). Lane j (0..10) owns column j.
__device__ inline void compose_one(const float* __restrict__ src,
                                   float* __restrict__ dst,
                                   int c, int lane) {
    const float* F = src + (size_t)(2 * c) * STRIDE;
    const float* G = src + (size_t)(2 * c + 1) * STRIDE;
    float colf[DIM], o[DIM];
    #pragma unroll
    for (int r = 0; r < DIM; ++r) colf[r] = F[lane * DIM + r];
    #pragma unroll
    for (int r = 0; r < DIM; ++r) {
        float acc = (lane == DIM) ? G[100 + r] : 0.f;
        #pragma unroll
        for (int k = 0; k < DIM; ++k)
            acc += G[k * DIM + r] * colf[k];
        o[r] = acc;
    }
    float* D = dst + (size_t)c * STRIDE;
    #pragma unroll
    for (int r = 0; r < DIM; ++r) D[lane * DIM + r] = o[r];
}

// ---------------------------------------------------------------------------
// K1 (proven round-0): block b composes layers [b*16, b*16+16) via a 4-level
// LDS tree: 16 -> 8 -> 4 -> 2 -> 1. One wave per compose.
// ---------------------------------------------------------------------------
__global__ __launch_bounds__(1024) void compose16(const float* __restrict__ Ws,
                                                  const float* __restrict__ bs,
                                                  float* __restrict__ wsout) {
    __shared__ float A[LPB * STRIDE];
    __shared__ float B[(LPB / 2) * STRIDE];
    const int tid = threadIdx.x;
    const int blk = blockIdx.x;

    for (int e = tid; e < LPB * 100; e += 1024) {
        int ll = e / 100, rem = e % 100;      // rem = r*10 + k
        int r = rem / 10, k = rem % 10;
        int l = blk * LPB + ll;
        float v = (l < NUM_LAYERS) ? Ws[(size_t)l * 100 + rem]
                                   : (r == k ? 1.f : 0.f);
        A[ll * STRIDE + k * DIM + r] = v;
    }
    for (int e = tid; e < LPB * DIM; e += 1024) {
        int ll = e / DIM, r = e % DIM;
        int l = blk * LPB + ll;
        float v = (l < NUM_LAYERS) ? bs[(size_t)l * DIM + r] : 0.f;
        A[ll * STRIDE + 100 + r] = v;
    }

    const int wave = tid >> 6, lane = tid & 63;
    const float* src = A;
    float* dst = B;
    for (int n = LPB / 2; n >= 1; n >>= 1) {   // n = 8,4,2,1
        __syncthreads();
        if (wave < n && lane <= DIM) compose_one(src, dst, wave, lane);
        const float* t = dst; dst = (float*)src; src = t;
    }
    __syncthreads();
    if (tid < 110) wsout[(size_t)blk * STRIDE + tid] = A[tid];
}

// ---------------------------------------------------------------------------
// K2 (proven round-0): one block folds the 63 chunk affines (padded to 64)
// via a 6-level tree. Writes the final affine ROW-major:
// aff[r*10+k] = M[r][k], aff[100+r] = c[r].
// ---------------------------------------------------------------------------
__global__ __launch_bounds__(1024) void compose_tree64(const float* __restrict__ wsin,
                                                       float* __restrict__ aff) {
    __shared__ float A[64 * STRIDE];
    __shared__ float B[32 * STRIDE];
    const int tid = threadIdx.x;

    for (int e = tid; e < 64 * STRIDE; e += 1024) {
        int chunk = e / STRIDE, pos = e % STRIDE;
        float v;
        if (pos >= 110)        v = 0.f;
        else if (chunk < NBLK) v = wsin[(size_t)chunk * STRIDE + pos];
        else v = (pos < 100 && (pos / 10 == pos % 10)) ? 1.f : 0.f;  // identity
        A[e] = v;
    }

    const int wave = tid >> 6, lane = tid & 63;
    const float* src = A;
    float* dst = B;
    for (int n = 32; n >= 1; n >>= 1) {        // n = 32,16,8,4,2,1
        __syncthreads();
        if (lane <= DIM)
            for (int c = wave; c < n; c += 16)
                compose_one(src, dst, c, lane);
        const float* t = dst; dst = (float*)src; src = t;
    }
    __syncthreads();
    if (tid < 110) {
        if (tid < 100) {
            int j = tid / DIM, r = tid % DIM;  // A[j*10+r] = M[r][j]
            aff[r * DIM + j] = A[tid];
        } else {
            aff[tid] = A[tid];                 // bias
        }
    }
}

// ---------------------------------------------------------------------------
// K3: out = M x + c. Round-5 barrier-free structure with the input staging
// replaced by DIRECT global->LDS DMA (global_load_lds width=16). Per wave:
// issue 5 DMA instructions (wave-uniform LDS base + lane*16 = exactly our
// linear layout), one vmcnt(0) sleep, then the data is already in LDS — no
// VGPR round-trip, no interleaved vmcnt/ds_write chains. Store path (LDS
// redistribute -> coalesced float4 stores) unchanged. No __syncthreads.
// LDS read stride 80 B = conflict-free (measured 0).
// ---------------------------------------------------------------------------
__global__ __launch_bounds__(256) void apply_affine(const float* __restrict__ x,
                                                    const float* __restrict__ aff,
                                                    float* __restrict__ out,
                                                    int nq4) {
    __shared__ float4 lds4[4][WQ4];
    __shared__ float4 s4[28];                  // 112 floats (110 used)
    const int tid  = threadIdx.x;
    const int w    = tid >> 6, lane = tid & 63;
    const float* __restrict__ s = (const float*)s4;

    const int q0 = blockIdx.x * TILE_Q4 + w * WQ4;   // this wave's float4 base
    const int rem = nq4 - q0;                  // float4s this wave owns
    if (rem <= 0) return;                      // empty tail wave (wave-uniform)

    // Redundant per-wave staging of the affine (identical values; covered by
    // this wave's own lgkm wait below).
    if (lane < 28) s4[lane] = ((const float4*)aff)[lane];

    const float4* __restrict__ xin = (const float4*)x + q0;
    float4* __restrict__ op = (float4*)out + q0;

    // ---- direct DMA: 5 x (64 lanes x 16 B) into this wave's LDS region ----
    // Per-lane global src (clamped for safety; batch divides evenly so the
    // clamp never fires in practice), wave-uniform LDS base.
    #pragma unroll
    for (int i = 0; i < 5; ++i) {
        int q = i * 64 + lane;
        gload_lds16(xin + (q < rem ? q : 0), &lds4[w][i * 64]);
    }

    // one sleep: DMA done (vmcnt) + this wave's s4/ds writes done (lgkm)
    asm volatile("s_waitcnt vmcnt(0) lgkmcnt(0)" ::: "memory");
    __builtin_amdgcn_sched_barrier(0);

    // thread reads its own 20 contiguous floats = rows {2T, 2T+1}
    float xv[20];
    #pragma unroll
    for (int i = 0; i < 5; ++i) {
        float4 v = lds4[w][5 * lane + i];
        xv[4*i+0] = v.x; xv[4*i+1] = v.y; xv[4*i+2] = v.z; xv[4*i+3] = v.w;
    }

    float o[20];
    #pragma unroll
    for (int rr = 0; rr < 2; ++rr)
        #pragma unroll
        for (int j = 0; j < DIM; ++j) {
            float acc = s[100 + j];
            #pragma unroll
            for (int k = 0; k < DIM; ++k)
                acc += s[j * DIM + k] * xv[rr * DIM + k];
            o[rr * DIM + j] = acc;
        }

    // write results back to the SAME per-lane addresses
    #pragma unroll
    for (int i = 0; i < 5; ++i)
        lds4[w][5 * lane + i] = make_float4(o[4*i+0], o[4*i+1], o[4*i+2], o[4*i+3]);

    asm volatile("s_waitcnt lgkmcnt(0)" ::: "memory");
    __builtin_amdgcn_sched_barrier(0);

    // coalesced, lane-predicated stores
    {
        float4 t0 = lds4[w][0 * 64 + lane];
        float4 t1 = lds4[w][1 * 64 + lane];
        float4 t2 = lds4[w][2 * 64 + lane];
        float4 t3 = lds4[w][3 * 64 + lane];
        float4 t4 = lds4[w][4 * 64 + lane];
        if (0 * 64 + lane < rem) op[0 * 64 + lane] = t0;
        if (1 * 64 + lane < rem) op[1 * 64 + lane] = t1;
        if (2 * 64 + lane < rem) op[2 * 64 + lane] = t2;
        if (3 * 64 + lane < rem) op[3 * 64 + lane] = t3;
        if (4 * 64 + lane < rem) op[4 * 64 + lane] = t4;
    }
}

extern "C" void kernel_launch(void* const* d_in, const int* in_sizes, int n_in,
                              void* d_out, int out_size, void* d_ws, size_t ws_size,
                              hipStream_t stream) {
    const float* x  = (const float*)d_in[0];   // [BATCH, 10]
    const float* Ws = (const float*)d_in[1];   // [1000, 10, 10]
    const float* bs = (const float*)d_in[2];   // [1000, 10]
    float* out = (float*)d_out;

    float* ws_chunks = (float*)d_ws;                      // NBLK * STRIDE floats
    float* ws_aff    = ws_chunks + NBLK * STRIDE;         // 112 floats (16B aligned)

    compose16<<<NBLK, 1024, 0, stream>>>(Ws, bs, ws_chunks);
    compose_tree64<<<1, 1024, 0, stream>>>(ws_chunks, ws_aff);

    const int nq4 = in_sizes[0] / 4;                      // in_sizes is in floats
    const int blocks = (nq4 + TILE_Q4 - 1) / TILE_Q4;
    apply_affine<<<blocks, 256, 0, stream>>>(x, ws_aff, out, nq4);
}